// Round 5
// baseline (294.091 us; speedup 1.0000x reference)
//
#include <hip/hip_runtime.h>
#include <cstdint>
#include <cstddef>

// Problem constants (fixed by the reference)
#define B_  2
#define T_  2048
#define D_  1024
#define H_  16
#define DH_ 64
#define M_  (B_*T_)   // 4096 rows when [B,T,D] flattened

typedef __bf16 bf16x8 __attribute__((ext_vector_type(8)));   // MFMA A/B frag (4 VGPRs)
typedef float  f32x4  __attribute__((ext_vector_type(4)));   // MFMA C/D frag
typedef unsigned short us4 __attribute__((ext_vector_type(4)));
typedef unsigned short us8 __attribute__((ext_vector_type(8)));
typedef unsigned short ushort_t;

__device__ __forceinline__ unsigned short f32_to_bf16_rne(float f) {
    unsigned u = __builtin_bit_cast(unsigned, f);
    u += 0x7FFFu + ((u >> 16) & 1u);
    return (unsigned short)(u >> 16);
}

// pack two f32 -> two bf16 in one u32 (round-half-up). 2 adds + 1 v_perm_b32.
__device__ __forceinline__ unsigned pack_bf16_2(float f0, float f1) {
    unsigned a = __builtin_bit_cast(unsigned, f0) + 0x8000u;
    unsigned b = __builtin_bit_cast(unsigned, f1) + 0x8000u;
    return __builtin_amdgcn_perm(b, a, 0x07060302u);   // (hi16(b)<<16) | hi16(a)
}

// async global->LDS, 16 B per lane. HW rule: LDS dest = wave-uniform base + lane*16.
// Global source is per-lane free: used for XOR chunk swizzles and key-row perms.
__device__ __forceinline__ void async16(const void* g, void* l) {
    __builtin_amdgcn_global_load_lds(
        (const __attribute__((address_space(1))) unsigned int*)(uintptr_t)g,
        (__attribute__((address_space(3))) unsigned int*)(uintptr_t)l, 16, 0, 0);
}

// ---------------- fp32 -> bf16 conversion (single launch, 7 tensors) ----------------
__global__ __launch_bounds__(256) void cvt_all(
    const float* __restrict__ i0, const float* __restrict__ i1, const float* __restrict__ i2,
    const float* __restrict__ i3, const float* __restrict__ i4, const float* __restrict__ i5,
    const float* __restrict__ i6,
    ushort_t* __restrict__ o0, ushort_t* __restrict__ o1, ushort_t* __restrict__ o2,
    ushort_t* __restrict__ o3, ushort_t* __restrict__ o4, ushort_t* __restrict__ o5,
    ushort_t* __restrict__ o6) {
    const int y = blockIdx.y;
    const float* in = y == 0 ? i0 : y == 1 ? i1 : y == 2 ? i2 : y == 3 ? i3
                    : y == 4 ? i4 : y == 5 ? i5 : i6;
    ushort_t* out  = y == 0 ? o0 : y == 1 ? o1 : y == 2 ? o2 : y == 3 ? o3
                    : y == 4 ? o4 : y == 5 ? o5 : o6;
    const int n = (y < 3) ? (M_ * D_) : (D_ * D_);
    int i = (blockIdx.x * 256 + threadIdx.x) * 4;
    if (i >= n) return;
    float4 f = *reinterpret_cast<const float4*>(in + i);
    unsigned lo = pack_bf16_2(f.x, f.y);
    unsigned hi = pack_bf16_2(f.z, f.w);
    *reinterpret_cast<unsigned long long*>(out + i) =
        (unsigned long long)lo | ((unsigned long long)hi << 32);
}

// ---------------- NT GEMM mainloop: BK=64, swizzled staging, 128x128 tile ----------------
__device__ __forceinline__ void gemm_mainloop(const ushort_t* __restrict__ A,
                                              const ushort_t* __restrict__ W,
                                              ushort_t* As, ushort_t* Bs,
                                              int m0, int n0, f32x4 acc[4][4]) {
    const int tid  = threadIdx.x;
    const int lc   = tid & 15;
    const int quad = (tid >> 4) & 3;
    const int wave = tid >> 6;
    const int wm = (wave >> 1) * 64, wn = (wave & 1) * 64;
    const int sw = lc & 7;   // row-derived swizzle (row&7 == lc&7 for frag rows)

    const f32x4 fzero = {0.f, 0.f, 0.f, 0.f};
#pragma unroll
    for (int mt = 0; mt < 4; ++mt)
#pragma unroll
        for (int nt = 0; nt < 4; ++nt) acc[mt][nt] = fzero;

    for (int kk = 0; kk < D_; kk += 64) {
        __syncthreads();
#pragma unroll
        for (int i = 0; i < 4; ++i) {
            const int j = i * 256 + tid;           // 1024 chunks of 16 B per tile
            const int r = j >> 3, c = (j & 7) ^ (r & 7);
            async16(A + (size_t)(m0 + r) * D_ + kk + c * 8, As + j * 8);
            async16(W + (size_t)(n0 + r) * D_ + kk + c * 8, Bs + j * 8);
        }
        __syncthreads();   // staging complete
#pragma unroll
        for (int ks = 0; ks < 2; ++ks) {
            bf16x8 af[4], bw[4];
#pragma unroll
            for (int mt = 0; mt < 4; ++mt)
                af[mt] = *reinterpret_cast<const bf16x8*>(
                    As + (wm + mt * 16 + lc) * 64 + (((ks * 4 + quad) ^ sw) * 8));
#pragma unroll
            for (int nt = 0; nt < 4; ++nt)
                bw[nt] = *reinterpret_cast<const bf16x8*>(
                    Bs + (wn + nt * 16 + lc) * 64 + (((ks * 4 + quad) ^ sw) * 8));
#pragma unroll
            for (int mt = 0; mt < 4; ++mt)
#pragma unroll
                for (int nt = 0; nt < 4; ++nt)
                    acc[mt][nt] = __builtin_amdgcn_mfma_f32_16x16x32_bf16(af[mt], bw[nt], acc[mt][nt], 0, 0, 0);
        }
    }
}

// Fused Q/K/V projection: grid (8, 32, 3). XCD-local remap.
__global__ __launch_bounds__(256, 3) void gemm_qkv(
    const ushort_t* __restrict__ qb, const ushort_t* __restrict__ kb, const ushort_t* __restrict__ vb,
    const ushort_t* __restrict__ wqb, const ushort_t* __restrict__ wkb, const ushort_t* __restrict__ wvb,
    ushort_t* __restrict__ qhb, ushort_t* __restrict__ khb, ushort_t* __restrict__ vtb) {
    __shared__ __align__(16) ushort_t As[128 * 64];
    __shared__ __align__(16) ushort_t Bs[128 * 64];
    __shared__ __align__(16) ushort_t Ts[4][16 * 80];   // per-wave epilogue relayout

    const int z = blockIdx.z;
    const ushort_t* A = z == 0 ? qb : z == 1 ? kb : vb;
    const ushort_t* W = z == 0 ? wqb : z == 1 ? wkb : wvb;
    const int yt = blockIdx.x + 8 * (blockIdx.y >> 3);   // A-tile (XCD-local)
    const int xt = blockIdx.y & 7;                       // W-col tile
    const int m0 = yt * 128, n0 = xt * 128;

    f32x4 acc[4][4];
    gemm_mainloop(A, W, As, Bs, m0, n0, acc);

    const int tid = threadIdx.x, lane = tid & 63, lc = tid & 15;
    const int quad = (tid >> 4) & 3, wave = tid >> 6;
    const int wm = (wave >> 1) * 64, wn = (wave & 1) * 64;
    const int mG = m0 + wm;
    const int bb = mG >> 11, t0 = mG & (T_ - 1);
    const int hh = (n0 + wn) >> 6;   // wave n-range = exactly one head

    if (z < 2) {
        ushort_t* outp = (z == 0 ? qhb : khb) + ((size_t)bb * H_ + hh) * T_ * DH_;
#pragma unroll
        for (int mt = 0; mt < 4; ++mt) {
#pragma unroll
            for (int nt = 0; nt < 4; ++nt)
#pragma unroll
                for (int r = 0; r < 4; ++r)
                    Ts[wave][(quad * 4 + r) * 80 + nt * 16 + lc] = f32_to_bf16_rne(acc[mt][nt][r]);
#pragma unroll
            for (int it = 0; it < 2; ++it) {
                const int c = it * 64 + lane;   // 128 chunks of 16 B
                const int row = c >> 3, c8 = c & 7;
                us8 vv = *reinterpret_cast<const us8*>(Ts[wave] + row * 80 + c8 * 8);
                *reinterpret_cast<us8*>(outp + (size_t)(t0 + mt * 16 + row) * DH_ + c8 * 8) = vv;
            }
        }
    } else {
        // V^T store [B,H,DH,T]
        ushort_t* base = vtb + ((size_t)bb * H_ + hh) * DH_ * T_;
#pragma unroll
        for (int mt = 0; mt < 4; ++mt) {
#pragma unroll
            for (int nt = 0; nt < 4; ++nt)
#pragma unroll
                for (int r = 0; r < 4; ++r)
                    Ts[wave][(nt * 16 + lc) * 16 + quad * 4 + r] = f32_to_bf16_rne(acc[mt][nt][r]);
#pragma unroll
            for (int it = 0; it < 2; ++it) {
                const int c = it * 64 + lane;
                const int nl = c >> 1, mh = c & 1;
                us8 vv = *reinterpret_cast<const us8*>(Ts[wave] + c * 8);
                *reinterpret_cast<us8*>(base + (size_t)nl * T_ + t0 + mt * 16 + mh * 8) = vv;
            }
        }
    }
}

// Final projection: 64x128 tiles, grid (8,64) -> 512 blocks (2/CU), fp32 out.
__global__ __launch_bounds__(256, 4) void gemm_wo(const ushort_t* __restrict__ A,
                                                  const ushort_t* __restrict__ W,
                                                  float* __restrict__ out) {
    __shared__ __align__(16) ushort_t As[64 * 64];
    __shared__ __align__(16) ushort_t Bs[128 * 64];
    const int yt = blockIdx.x + 8 * (blockIdx.y >> 3);   // 64 A-tiles, XCD-local
    const int xt = blockIdx.y & 7;
    const int m0 = yt * 64, n0 = xt * 128;

    const int tid = threadIdx.x, lc = tid & 15;
    const int quad = (tid >> 4) & 3, wave = tid >> 6;
    const int wm = (wave >> 1) * 32, wn = (wave & 1) * 64;
    const int sw = lc & 7;

    const f32x4 fzero = {0.f, 0.f, 0.f, 0.f};
    f32x4 acc[2][4];
#pragma unroll
    for (int mt = 0; mt < 2; ++mt)
#pragma unroll
        for (int nt = 0; nt < 4; ++nt) acc[mt][nt] = fzero;

    for (int kk = 0; kk < D_; kk += 64) {
        __syncthreads();
#pragma unroll
        for (int i = 0; i < 2; ++i) {
            const int j = i * 256 + tid;           // 512 chunks (A: 64 rows)
            const int r = j >> 3, c = (j & 7) ^ (r & 7);
            async16(A + (size_t)(m0 + r) * D_ + kk + c * 8, As + j * 8);
        }
#pragma unroll
        for (int i = 0; i < 4; ++i) {
            const int j = i * 256 + tid;           // 1024 chunks (B: 128 rows)
            const int r = j >> 3, c = (j & 7) ^ (r & 7);
            async16(W + (size_t)(n0 + r) * D_ + kk + c * 8, Bs + j * 8);
        }
        __syncthreads();
#pragma unroll
        for (int ks = 0; ks < 2; ++ks) {
            bf16x8 af[2], bw[4];
#pragma unroll
            for (int mt = 0; mt < 2; ++mt)
                af[mt] = *reinterpret_cast<const bf16x8*>(
                    As + (wm + mt * 16 + lc) * 64 + (((ks * 4 + quad) ^ sw) * 8));
#pragma unroll
            for (int nt = 0; nt < 4; ++nt)
                bw[nt] = *reinterpret_cast<const bf16x8*>(
                    Bs + (wn + nt * 16 + lc) * 64 + (((ks * 4 + quad) ^ sw) * 8));
#pragma unroll
            for (int mt = 0; mt < 2; ++mt)
#pragma unroll
                for (int nt = 0; nt < 4; ++nt)
                    acc[mt][nt] = __builtin_amdgcn_mfma_f32_16x16x32_bf16(af[mt], bw[nt], acc[mt][nt], 0, 0, 0);
        }
    }

#pragma unroll
    for (int mt = 0; mt < 2; ++mt)
#pragma unroll
        for (int nt = 0; nt < 4; ++nt)
#pragma unroll
            for (int r = 0; r < 4; ++r) {
                const int m = m0 + wm + mt * 16 + quad * 4 + r;
                const int n = n0 + wn + nt * 16 + lc;
                out[(size_t)m * D_ + n] = acc[mt][nt][r];
            }
}

// ---------------- causal flash attention v10 ----------------
// v9 was latency-bound: occupancy 16.5% (2 blocks/CU), MfmaUtil 15%, HBM 6%, and
// the LDS footprint (41984 B) was 1 KB over the 40960 B threshold for 4 blocks/CU.
// v10: P scratch restrided 72 -> 64 with a 16 B-unit XOR swizzle
// (physical_unit = logical_unit ^ (row&7)) to keep P reads/writes bank-balanced
// at the power-of-2 stride. LDS = 16384 KV + 4*16*64 P = 40960 B exactly ->
// 4 blocks/CU. __launch_bounds__(256,4) caps VGPR at 128 (v9 measured 96, so
// 32 regs headroom; WRITE_SIZE is the spill tripwire). Everything else = v9.
__global__ __launch_bounds__(256, 4) void attn10(const ushort_t* __restrict__ Qh,
                                                 const ushort_t* __restrict__ Kh,
                                                 const ushort_t* __restrict__ Vt,
                                                 ushort_t* __restrict__ Ao) {
    // K: 2 tiles x 4096 ush | V: 2 tiles | P: 4 waves x 16 rows x stride 64 (swizzled)
    __shared__ __align__(16) ushort_t smem[16384 + 4 * 16 * 64];   // 40960 B exactly

    const int tid = threadIdx.x, lc = tid & 15;
    const int quad = (tid >> 4) & 3, wave = tid >> 6;   // 0..3
    const int grp = wave >> 1, sub = wave & 1;
    const int sw = lc & 7;

    const int L = blockIdx.x;
    const int xcd = L & 7, s = L >> 3;       // s in 0..127
    const int qt = 31 - (s >> 2);            // OUTER: longest q-tiles dispatched first
    const int bh = xcd + 8 * (s & 3);        // 4 bh per XCD
    const int bb = bh >> 4, hh = bh & 15;
    const int q0 = qt * 64, nkt = qt + 1;
    const int nIt = (nkt + 1) >> 1;
    const int mbase = q0 + sub * 32;

    const ushort_t* Qp = Qh + (size_t)bh * T_ * DH_;
    const ushort_t* Kp = Kh + (size_t)bh * T_ * DH_;
    const ushort_t* Vp = Vt + (size_t)bh * DH_ * T_;
    const float SC2 = 0.18033688f;   // log2(e)/sqrt(64)
    const f32x4 fzero = {0.f, 0.f, 0.f, 0.f};
    ushort_t* Pw = smem + 16384 + wave * (16 * 64);

    // Q A-frags (32 rows -> 2 m-tiles), loop-invariant
    bf16x8 aq[2][2];
#pragma unroll
    for (int mt = 0; mt < 2; ++mt) {
        const ushort_t* qrow = Qp + (size_t)(mbase + mt * 16 + lc) * DH_ + quad * 8;
        aq[mt][0] = *reinterpret_cast<const bf16x8*>(qrow);
        aq[mt][1] = *reinterpret_cast<const bf16x8*>(qrow + 32);
    }

    f32x4 o[2][4];
    float lsum[2][4];
#pragma unroll
    for (int mt = 0; mt < 2; ++mt) {
#pragma unroll
        for (int ct = 0; ct < 4; ++ct) o[mt][ct] = fzero;
#pragma unroll
        for (int r = 0; r < 4; ++r) lsum[mt][r] = 0.f;
    }

    // ---- per-thread staging geometry (round-invariant). Each thread stages
    // chunk tid and chunk 256+tid of each of the 4 tile regions. ----
    const int jj0 = tid,        jj1 = 256 + tid;
    const int rr0 = jj0 >> 3,   rr1 = jj1 >> 3;
    const int cc0 = (jj0 & 7) ^ (rr0 & 7), cc1 = (jj1 & 7) ^ (rr1 & 7);
    const int kp0 = 4 * (rr0 & 15) + (rr0 >> 4);   // K key-row permutation
    const int kp1 = 4 * (rr1 & 15) + (rr1 >> 4);
    const ushort_t* pK0 = Kp + kp0 * DH_ + cc0 * 8;         // + kt*4096
    const ushort_t* pK1 = Kp + kp1 * DH_ + cc1 * 8;
    const ushort_t* pV0 = Vp + (size_t)rr0 * T_ + cc0 * 8;  // + kt*64
    const ushort_t* pV1 = Vp + (size_t)rr1 * T_ + cc1 * 8;

    // 8 NAMED staging registers (rule #20: never an array)
    us8 sK0a, sK0b, sK1a, sK1b, sV0a, sV0b, sV1a, sV1b;

#define LOAD_KV(T0, T1)                                                      \
    {                                                                        \
        sK0a = *reinterpret_cast<const us8*>(pK0 + (T0) * 4096);             \
        sK0b = *reinterpret_cast<const us8*>(pK1 + (T0) * 4096);             \
        sK1a = *reinterpret_cast<const us8*>(pK0 + (T1) * 4096);             \
        sK1b = *reinterpret_cast<const us8*>(pK1 + (T1) * 4096);             \
        sV0a = *reinterpret_cast<const us8*>(pV0 + (T0) * 64);               \
        sV0b = *reinterpret_cast<const us8*>(pV1 + (T0) * 64);               \
        sV1a = *reinterpret_cast<const us8*>(pV0 + (T1) * 64);               \
        sV1b = *reinterpret_cast<const us8*>(pV1 + (T1) * 64);               \
    }

#define WRITE_KV()                                                           \
    {                                                                        \
        *reinterpret_cast<us8*>(smem + jj0 * 8)          = sK0a;             \
        *reinterpret_cast<us8*>(smem + jj1 * 8)          = sK0b;             \
        *reinterpret_cast<us8*>(smem + 4096 + jj0 * 8)   = sK1a;             \
        *reinterpret_cast<us8*>(smem + 4096 + jj1 * 8)   = sK1b;             \
        *reinterpret_cast<us8*>(smem + 8192 + jj0 * 8)   = sV0a;             \
        *reinterpret_cast<us8*>(smem + 8192 + jj1 * 8)   = sV0b;             \
        *reinterpret_cast<us8*>(smem + 12288 + jj0 * 8)  = sV1a;             \
        *reinterpret_cast<us8*>(smem + 12288 + jj1 * 8)  = sV1b;             \
    }

    // One k-tile of compute for this thread's group. diag folds to constant
    // at both inline sites (false in main loop, kt==qt in the tail).
    auto compute = [&](const int kt, const bool diag) {
        const int k0 = kt * 64;
        const ushort_t* Kt    = smem + grp * 4096;
        const ushort_t* Vtile = smem + 8192 + grp * 4096;

        // ---- S = Q K^T (K frags shared across m-tiles) ----
        f32x4 sc[2][4];
        __builtin_amdgcn_s_setprio(1);
#pragma unroll
        for (int ct = 0; ct < 4; ++ct) {
            const ushort_t* kr = Kt + (ct * 16 + lc) * 64;
            bf16x8 bk0 = *reinterpret_cast<const bf16x8*>(kr + ((quad ^ sw) * 8));
            bf16x8 bk1 = *reinterpret_cast<const bf16x8*>(kr + (((4 + quad) ^ sw) * 8));
#pragma unroll
            for (int mt = 0; mt < 2; ++mt) {
                sc[mt][ct] = __builtin_amdgcn_mfma_f32_16x16x32_bf16(aq[mt][0], bk0, fzero, 0, 0, 0);
                sc[mt][ct] = __builtin_amdgcn_mfma_f32_16x16x32_bf16(aq[mt][1], bk1, sc[mt][ct], 0, 0, 0);
            }
        }
        __builtin_amdgcn_s_setprio(0);

        // ---- V B-frags (needed only for PV; loaded here so the ds_reads
        // overlap softmax and don't hold 32 VGPRs across QK^T) ----
        bf16x8 bv[4][2];
#pragma unroll
        for (int ct = 0; ct < 4; ++ct) {
            const ushort_t* vr = Vtile + (ct * 16 + lc) * 64;
            bv[ct][0] = *reinterpret_cast<const bf16x8*>(vr + ((quad ^ sw) * 8));
            bv[ct][1] = *reinterpret_cast<const bf16x8*>(vr + (((4 + quad) ^ sw) * 8));
        }

        // ---- per m-tile: fixed-max softmax -> packed P write -> PV ----
#pragma unroll
        for (int mt = 0; mt < 2; ++mt) {
            float e[4][4];
            if (diag) {   // only the diagonal tile masks
#pragma unroll
                for (int ct = 0; ct < 4; ++ct) {
                    const int key = k0 + 4 * lc + ct;   // permuted key of this col
#pragma unroll
                    for (int r = 0; r < 4; ++r) {
                        const int row = mbase + mt * 16 + quad * 4 + r;
                        e[ct][r] = (key <= row) ? __builtin_amdgcn_exp2f(sc[mt][ct][r] * SC2) : 0.f;
                    }
                }
            } else {
#pragma unroll
                for (int ct = 0; ct < 4; ++ct)
#pragma unroll
                    for (int r = 0; r < 4; ++r)
                        e[ct][r] = __builtin_amdgcn_exp2f(sc[mt][ct][r] * SC2);
            }
            // P write: row-major 16 x 64 keys, 16 B-unit XOR swizzle
            // (physical_unit = (lc>>1) ^ (row&7)) keeps stride-64 bank-balanced.
#pragma unroll
            for (int r = 0; r < 4; ++r) {
                lsum[mt][r] += (e[0][r] + e[1][r]) + (e[2][r] + e[3][r]);
                unsigned lo = pack_bf16_2(e[0][r], e[1][r]);
                unsigned hi = pack_bf16_2(e[2][r], e[3][r]);
                const int row = quad * 4 + r;
                const int punit = (lc >> 1) ^ (row & 7);
                *reinterpret_cast<unsigned long long*>(
                    Pw + row * 64 + punit * 8 + (lc & 1) * 4) =
                    (unsigned long long)lo | ((unsigned long long)hi << 32);
            }
            // P read: q-row = lc; frag0 = keys quad*8.., frag1 = keys 32+quad*8..
            bf16x8 ap0 = *reinterpret_cast<const bf16x8*>(
                Pw + lc * 64 + ((quad ^ (lc & 7)) * 8));
            bf16x8 ap1 = *reinterpret_cast<const bf16x8*>(
                Pw + lc * 64 + (((4 + quad) ^ (lc & 7)) * 8));
            __builtin_amdgcn_s_setprio(1);
#pragma unroll
            for (int ct = 0; ct < 4; ++ct) {
                o[mt][ct] = __builtin_amdgcn_mfma_f32_16x16x32_bf16(ap0, bv[ct][0], o[mt][ct], 0, 0, 0);
                o[mt][ct] = __builtin_amdgcn_mfma_f32_16x16x32_bf16(ap1, bv[ct][1], o[mt][ct], 0, 0, 0);
            }
            __builtin_amdgcn_s_setprio(0);
        }
    };

    // ---- prologue: stage round 0 ----
    {
        const int t1 = (nkt > 1) ? 1 : 0;
        LOAD_KV(0, t1);
        WRITE_KV();
        __syncthreads();   // round-0 tiles visible
    }

    // ---- main loop: straight-line, unmasked, unguarded ----
    for (int it = 0; it < nIt - 1; ++it) {
        const int n0t = 2 * it + 2;
        const int n1t = (n0t + 1 < nkt) ? n0t + 1 : n0t;
        LOAD_KV(n0t, n1t);            // next round, in flight under compute
        compute(2 * it + grp, false); // kt < qt guaranteed here
        __syncthreads();              // all waves done reading current tiles
        WRITE_KV();                   // vmcnt wait is compiler-inserted here
        __syncthreads();              // next round's tiles visible
    }

    // ---- peeled last round: guard + causal mask, no prefetch ----
    {
        const int ktL = 2 * (nIt - 1) + grp;
        if (ktL < nkt) compute(ktL, ktL == qt);
    }
#undef LOAD_KV
#undef WRITE_KV

    // ---- combine the two k-groups via LDS; group 1 normalizes; coalesced store ----
    __syncthreads();   // compute done; K/V LDS reusable as scratch
    float* Osh = (float*)smem;             // 16 KB (K region)
    float* Lsh = (float*)(smem + 8192);    // 4 KB (V region)
    ushort_t* Fsh = smem + 16384;          // 8 KB final bf16 tile (P region reuse)
    if (grp == 0) {
#pragma unroll
        for (int mt = 0; mt < 2; ++mt) {
#pragma unroll
            for (int ct = 0; ct < 4; ++ct)
#pragma unroll
                for (int r = 0; r < 4; ++r)
                    Osh[(sub * 32 + mt * 16 + quad * 4 + r) * 64 + ct * 16 + lc] = o[mt][ct][r];
#pragma unroll
            for (int r = 0; r < 4; ++r)
                Lsh[(sub * 32 + mt * 16 + quad * 4 + r) * 16 + lc] = lsum[mt][r];
        }
    }
    __syncthreads();
    if (grp == 1) {
#pragma unroll
        for (int mt = 0; mt < 2; ++mt) {
            float inv[4];
#pragma unroll
            for (int r = 0; r < 4; ++r) {
                float l = lsum[mt][r] + Lsh[(sub * 32 + mt * 16 + quad * 4 + r) * 16 + lc];
#pragma unroll
                for (int d = 1; d < 16; d <<= 1) l += __shfl_xor(l, d);
                inv[r] = 1.0f / l;
            }
#pragma unroll
            for (int ct = 0; ct < 4; ++ct)
#pragma unroll
                for (int r = 0; r < 4; ++r) {
                    const int row = sub * 32 + mt * 16 + quad * 4 + r;   // 0..63 local
                    const float ov = o[mt][ct][r] + Osh[row * 64 + ct * 16 + lc];
                    const int cu = ct * 16 + lc;
                    // XOR-swizzle the 8-ushort chunk index by row so the
                    // vectorized read below is bank-conflict-free
                    Fsh[row * 64 + ((cu & 7) | ((((cu >> 3) ^ row) & 7) << 3))] =
                        f32_to_bf16_rne(ov * inv[r]);
                }
        }
    }
    __syncthreads();
    // 64 rows x 128 B contiguous stores (full sectors): 512 chunks of 16 B
#pragma unroll
    for (int i = 0; i < 2; ++i) {
        const int j = i * 256 + tid;
        const int row = j >> 3, c8 = j & 7;
        us8 vv = *reinterpret_cast<const us8*>(Fsh + row * 64 + ((c8 ^ row) & 7) * 8);
        *reinterpret_cast<us8*>(Ao + ((size_t)bb * T_ + q0 + row) * D_ + hh * DH_ + c8 * 8) = vv;
    }
}

// ---------------- launch ----------------
extern "C" void kernel_launch(void* const* d_in, const int* in_sizes, int n_in,
                              void* d_out, int out_size, void* d_ws, size_t ws_size,
                              hipStream_t stream) {
    const float* q  = (const float*)d_in[0];
    const float* k  = (const float*)d_in[1];
    const float* v  = (const float*)d_in[2];
    const float* wq = (const float*)d_in[3];
    const float* wk = (const float*)d_in[4];
    const float* wv = (const float*)d_in[5];
    const float* wo = (const float*)d_in[6];

    char* ws = (char*)d_ws;
    size_t off = 0;
    auto alloc = [&](size_t bytes) -> char* {
        char* p = ws + off;
        off += (bytes + 255) & ~(size_t)255;
        return p;
    };
    ushort_t* qb  = (ushort_t*)alloc((size_t)M_ * D_ * 2);
    ushort_t* kb  = (ushort_t*)alloc((size_t)M_ * D_ * 2);
    ushort_t* vb  = (ushort_t*)alloc((size_t)M_ * D_ * 2);
    ushort_t* wqb = (ushort_t*)alloc((size_t)D_ * D_ * 2);
    ushort_t* wkb = (ushort_t*)alloc((size_t)D_ * D_ * 2);
    ushort_t* wvb = (ushort_t*)alloc((size_t)D_ * D_ * 2);
    ushort_t* wob = (ushort_t*)alloc((size_t)D_ * D_ * 2);
    ushort_t* qhb = (ushort_t*)alloc((size_t)M_ * D_ * 2);  // [B,H,T,DH]
    ushort_t* khb = (ushort_t*)alloc((size_t)M_ * D_ * 2);  // [B,H,T,DH]
    ushort_t* vtb = (ushort_t*)alloc((size_t)M_ * D_ * 2);  // [B,H,DH,T]
    ushort_t* aob = (ushort_t*)alloc((size_t)M_ * D_ * 2);  // [B,T,D]

    cvt_all<<<dim3(4096, 7), 256, 0, stream>>>(q, k, v, wq, wk, wv, wo,
                                               qb, kb, vb, wqb, wkb, wvb, wob);

    gemm_qkv<<<dim3(8, 32, 3), 256, 0, stream>>>(qb, kb, vb, wqb, wkb, wvb, qhb, khb, vtb);

    attn10<<<dim3(1024), 256, 0, stream>>>(qhb, khb, vtb, aob);

    gemm_wo<<<dim3(8, 64), 256, 0, stream>>>(aob, wob, (float*)d_out);
}

// Round 6
// 190.098 us; speedup vs baseline: 1.5470x; 1.5470x over previous
//
#include <hip/hip_runtime.h>
#include <cstdint>
#include <cstddef>

// Problem constants (fixed by the reference)
#define B_  2
#define T_  2048
#define D_  1024
#define H_  16
#define DH_ 64
#define M_  (B_*T_)   // 4096 rows when [B,T,D] flattened

typedef __bf16 bf16x8 __attribute__((ext_vector_type(8)));   // MFMA A/B frag (4 VGPRs)
typedef float  f32x4  __attribute__((ext_vector_type(4)));   // MFMA C/D frag
typedef unsigned short us4 __attribute__((ext_vector_type(4)));
typedef unsigned short us8 __attribute__((ext_vector_type(8)));
typedef unsigned short ushort_t;

__device__ __forceinline__ unsigned short f32_to_bf16_rne(float f) {
    unsigned u = __builtin_bit_cast(unsigned, f);
    u += 0x7FFFu + ((u >> 16) & 1u);
    return (unsigned short)(u >> 16);
}

// pack two f32 -> two bf16 in one u32 (round-half-up). 2 adds + 1 v_perm_b32.
__device__ __forceinline__ unsigned pack_bf16_2(float f0, float f1) {
    unsigned a = __builtin_bit_cast(unsigned, f0) + 0x8000u;
    unsigned b = __builtin_bit_cast(unsigned, f1) + 0x8000u;
    return __builtin_amdgcn_perm(b, a, 0x07060302u);   // (hi16(b)<<16) | hi16(a)
}

// async global->LDS, 16 B per lane. HW rule: LDS dest = wave-uniform base + lane*16.
// Global source is per-lane free: used for XOR chunk swizzles and key-row perms.
__device__ __forceinline__ void async16(const void* g, void* l) {
    __builtin_amdgcn_global_load_lds(
        (const __attribute__((address_space(1))) unsigned int*)(uintptr_t)g,
        (__attribute__((address_space(3))) unsigned int*)(uintptr_t)l, 16, 0, 0);
}

// ---------------- fp32 -> bf16 conversion (single launch, 7 tensors) ----------------
__global__ __launch_bounds__(256) void cvt_all(
    const float* __restrict__ i0, const float* __restrict__ i1, const float* __restrict__ i2,
    const float* __restrict__ i3, const float* __restrict__ i4, const float* __restrict__ i5,
    const float* __restrict__ i6,
    ushort_t* __restrict__ o0, ushort_t* __restrict__ o1, ushort_t* __restrict__ o2,
    ushort_t* __restrict__ o3, ushort_t* __restrict__ o4, ushort_t* __restrict__ o5,
    ushort_t* __restrict__ o6) {
    const int y = blockIdx.y;
    const float* in = y == 0 ? i0 : y == 1 ? i1 : y == 2 ? i2 : y == 3 ? i3
                    : y == 4 ? i4 : y == 5 ? i5 : i6;
    ushort_t* out  = y == 0 ? o0 : y == 1 ? o1 : y == 2 ? o2 : y == 3 ? o3
                    : y == 4 ? o4 : y == 5 ? o5 : o6;
    const int n = (y < 3) ? (M_ * D_) : (D_ * D_);
    int i = (blockIdx.x * 256 + threadIdx.x) * 4;
    if (i >= n) return;
    float4 f = *reinterpret_cast<const float4*>(in + i);
    unsigned lo = pack_bf16_2(f.x, f.y);
    unsigned hi = pack_bf16_2(f.z, f.w);
    *reinterpret_cast<unsigned long long*>(out + i) =
        (unsigned long long)lo | ((unsigned long long)hi << 32);
}

// ---------------- NT GEMM mainloop: BK=64, swizzled staging, 128x128 tile ----------------
__device__ __forceinline__ void gemm_mainloop(const ushort_t* __restrict__ A,
                                              const ushort_t* __restrict__ W,
                                              ushort_t* As, ushort_t* Bs,
                                              int m0, int n0, f32x4 acc[4][4]) {
    const int tid  = threadIdx.x;
    const int lc   = tid & 15;
    const int quad = (tid >> 4) & 3;
    const int wave = tid >> 6;
    const int wm = (wave >> 1) * 64, wn = (wave & 1) * 64;
    const int sw = lc & 7;   // row-derived swizzle (row&7 == lc&7 for frag rows)

    const f32x4 fzero = {0.f, 0.f, 0.f, 0.f};
#pragma unroll
    for (int mt = 0; mt < 4; ++mt)
#pragma unroll
        for (int nt = 0; nt < 4; ++nt) acc[mt][nt] = fzero;

    for (int kk = 0; kk < D_; kk += 64) {
        __syncthreads();
#pragma unroll
        for (int i = 0; i < 4; ++i) {
            const int j = i * 256 + tid;           // 1024 chunks of 16 B per tile
            const int r = j >> 3, c = (j & 7) ^ (r & 7);
            async16(A + (size_t)(m0 + r) * D_ + kk + c * 8, As + j * 8);
            async16(W + (size_t)(n0 + r) * D_ + kk + c * 8, Bs + j * 8);
        }
        __syncthreads();   // staging complete
#pragma unroll
        for (int ks = 0; ks < 2; ++ks) {
            bf16x8 af[4], bw[4];
#pragma unroll
            for (int mt = 0; mt < 4; ++mt)
                af[mt] = *reinterpret_cast<const bf16x8*>(
                    As + (wm + mt * 16 + lc) * 64 + (((ks * 4 + quad) ^ sw) * 8));
#pragma unroll
            for (int nt = 0; nt < 4; ++nt)
                bw[nt] = *reinterpret_cast<const bf16x8*>(
                    Bs + (wn + nt * 16 + lc) * 64 + (((ks * 4 + quad) ^ sw) * 8));
#pragma unroll
            for (int mt = 0; mt < 4; ++mt)
#pragma unroll
                for (int nt = 0; nt < 4; ++nt)
                    acc[mt][nt] = __builtin_amdgcn_mfma_f32_16x16x32_bf16(af[mt], bw[nt], acc[mt][nt], 0, 0, 0);
        }
    }
}

// Fused Q/K/V projection: grid (8, 32, 3). XCD-local remap.
__global__ __launch_bounds__(256, 3) void gemm_qkv(
    const ushort_t* __restrict__ qb, const ushort_t* __restrict__ kb, const ushort_t* __restrict__ vb,
    const ushort_t* __restrict__ wqb, const ushort_t* __restrict__ wkb, const ushort_t* __restrict__ wvb,
    ushort_t* __restrict__ qhb, ushort_t* __restrict__ khb, ushort_t* __restrict__ vtb) {
    __shared__ __align__(16) ushort_t As[128 * 64];
    __shared__ __align__(16) ushort_t Bs[128 * 64];
    __shared__ __align__(16) ushort_t Ts[4][16 * 80];   // per-wave epilogue relayout

    const int z = blockIdx.z;
    const ushort_t* A = z == 0 ? qb : z == 1 ? kb : vb;
    const ushort_t* W = z == 0 ? wqb : z == 1 ? wkb : wvb;
    const int yt = blockIdx.x + 8 * (blockIdx.y >> 3);   // A-tile (XCD-local)
    const int xt = blockIdx.y & 7;                       // W-col tile
    const int m0 = yt * 128, n0 = xt * 128;

    f32x4 acc[4][4];
    gemm_mainloop(A, W, As, Bs, m0, n0, acc);

    const int tid = threadIdx.x, lane = tid & 63, lc = tid & 15;
    const int quad = (tid >> 4) & 3, wave = tid >> 6;
    const int wm = (wave >> 1) * 64, wn = (wave & 1) * 64;
    const int mG = m0 + wm;
    const int bb = mG >> 11, t0 = mG & (T_ - 1);
    const int hh = (n0 + wn) >> 6;   // wave n-range = exactly one head

    if (z < 2) {
        ushort_t* outp = (z == 0 ? qhb : khb) + ((size_t)bb * H_ + hh) * T_ * DH_;
#pragma unroll
        for (int mt = 0; mt < 4; ++mt) {
#pragma unroll
            for (int nt = 0; nt < 4; ++nt)
#pragma unroll
                for (int r = 0; r < 4; ++r)
                    Ts[wave][(quad * 4 + r) * 80 + nt * 16 + lc] = f32_to_bf16_rne(acc[mt][nt][r]);
#pragma unroll
            for (int it = 0; it < 2; ++it) {
                const int c = it * 64 + lane;   // 128 chunks of 16 B
                const int row = c >> 3, c8 = c & 7;
                us8 vv = *reinterpret_cast<const us8*>(Ts[wave] + row * 80 + c8 * 8);
                *reinterpret_cast<us8*>(outp + (size_t)(t0 + mt * 16 + row) * DH_ + c8 * 8) = vv;
            }
        }
    } else {
        // V^T store [B,H,DH,T]
        ushort_t* base = vtb + ((size_t)bb * H_ + hh) * DH_ * T_;
#pragma unroll
        for (int mt = 0; mt < 4; ++mt) {
#pragma unroll
            for (int nt = 0; nt < 4; ++nt)
#pragma unroll
                for (int r = 0; r < 4; ++r)
                    Ts[wave][(nt * 16 + lc) * 16 + quad * 4 + r] = f32_to_bf16_rne(acc[mt][nt][r]);
#pragma unroll
            for (int it = 0; it < 2; ++it) {
                const int c = it * 64 + lane;
                const int nl = c >> 1, mh = c & 1;
                us8 vv = *reinterpret_cast<const us8*>(Ts[wave] + c * 8);
                *reinterpret_cast<us8*>(base + (size_t)nl * T_ + t0 + mt * 16 + mh * 8) = vv;
            }
        }
    }
}

// Final projection: 64x128 tiles, grid (8,64) -> 512 blocks (2/CU), fp32 out.
__global__ __launch_bounds__(256, 4) void gemm_wo(const ushort_t* __restrict__ A,
                                                  const ushort_t* __restrict__ W,
                                                  float* __restrict__ out) {
    __shared__ __align__(16) ushort_t As[64 * 64];
    __shared__ __align__(16) ushort_t Bs[128 * 64];
    const int yt = blockIdx.x + 8 * (blockIdx.y >> 3);   // 64 A-tiles, XCD-local
    const int xt = blockIdx.y & 7;
    const int m0 = yt * 64, n0 = xt * 128;

    const int tid = threadIdx.x, lc = tid & 15;
    const int quad = (tid >> 4) & 3, wave = tid >> 6;
    const int wm = (wave >> 1) * 32, wn = (wave & 1) * 64;
    const int sw = lc & 7;

    const f32x4 fzero = {0.f, 0.f, 0.f, 0.f};
    f32x4 acc[2][4];
#pragma unroll
    for (int mt = 0; mt < 2; ++mt)
#pragma unroll
        for (int nt = 0; nt < 4; ++nt) acc[mt][nt] = fzero;

    for (int kk = 0; kk < D_; kk += 64) {
        __syncthreads();
#pragma unroll
        for (int i = 0; i < 2; ++i) {
            const int j = i * 256 + tid;           // 512 chunks (A: 64 rows)
            const int r = j >> 3, c = (j & 7) ^ (r & 7);
            async16(A + (size_t)(m0 + r) * D_ + kk + c * 8, As + j * 8);
        }
#pragma unroll
        for (int i = 0; i < 4; ++i) {
            const int j = i * 256 + tid;           // 1024 chunks (B: 128 rows)
            const int r = j >> 3, c = (j & 7) ^ (r & 7);
            async16(W + (size_t)(n0 + r) * D_ + kk + c * 8, Bs + j * 8);
        }
        __syncthreads();
#pragma unroll
        for (int ks = 0; ks < 2; ++ks) {
            bf16x8 af[2], bw[4];
#pragma unroll
            for (int mt = 0; mt < 2; ++mt)
                af[mt] = *reinterpret_cast<const bf16x8*>(
                    As + (wm + mt * 16 + lc) * 64 + (((ks * 4 + quad) ^ sw) * 8));
#pragma unroll
            for (int nt = 0; nt < 4; ++nt)
                bw[nt] = *reinterpret_cast<const bf16x8*>(
                    Bs + (wn + nt * 16 + lc) * 64 + (((ks * 4 + quad) ^ sw) * 8));
#pragma unroll
            for (int mt = 0; mt < 2; ++mt)
#pragma unroll
                for (int nt = 0; nt < 4; ++nt)
                    acc[mt][nt] = __builtin_amdgcn_mfma_f32_16x16x32_bf16(af[mt], bw[nt], acc[mt][nt], 0, 0, 0);
        }
    }

#pragma unroll
    for (int mt = 0; mt < 2; ++mt)
#pragma unroll
        for (int nt = 0; nt < 4; ++nt)
#pragma unroll
            for (int r = 0; r < 4; ++r) {
                const int m = m0 + wm + mt * 16 + quad * 4 + r;
                const int n = n0 + wn + nt * 16 + lc;
                out[(size_t)m * D_ + n] = acc[mt][nt][r];
            }
}

// ---------------- causal flash attention v11 ----------------
// v10's __launch_bounds__(256,4) made the allocator drop to the 64-VGPR occupancy
// quantum and spill everything (WRITE_SIZE 338 MB). v11 = v10's layout with v9's
// proven-clean __launch_bounds__(256,2): VGPR ~96 (5 waves/EU by VGPR), so the
// occupancy limiter is LDS (40960 B = exactly 4 blocks/CU) — occupancy doubles
// WITHOUT asking the register allocator for anything beyond its natural fit.
// Keeps v10's P stride-64 XOR-swizzled layout (bank conflicts 868K -> 328K).
__global__ __launch_bounds__(256, 2) void attn11(const ushort_t* __restrict__ Qh,
                                                 const ushort_t* __restrict__ Kh,
                                                 const ushort_t* __restrict__ Vt,
                                                 ushort_t* __restrict__ Ao) {
    // K: 2 tiles x 4096 ush | V: 2 tiles | P: 4 waves x 16 rows x stride 64 (swizzled)
    __shared__ __align__(16) ushort_t smem[16384 + 4 * 16 * 64];   // 40960 B exactly

    const int tid = threadIdx.x, lc = tid & 15;
    const int quad = (tid >> 4) & 3, wave = tid >> 6;   // 0..3
    const int grp = wave >> 1, sub = wave & 1;
    const int sw = lc & 7;

    const int L = blockIdx.x;
    const int xcd = L & 7, s = L >> 3;       // s in 0..127
    const int qt = 31 - (s >> 2);            // OUTER: longest q-tiles dispatched first
    const int bh = xcd + 8 * (s & 3);        // 4 bh per XCD
    const int bb = bh >> 4, hh = bh & 15;
    const int q0 = qt * 64, nkt = qt + 1;
    const int nIt = (nkt + 1) >> 1;
    const int mbase = q0 + sub * 32;

    const ushort_t* Qp = Qh + (size_t)bh * T_ * DH_;
    const ushort_t* Kp = Kh + (size_t)bh * T_ * DH_;
    const ushort_t* Vp = Vt + (size_t)bh * DH_ * T_;
    const float SC2 = 0.18033688f;   // log2(e)/sqrt(64)
    const f32x4 fzero = {0.f, 0.f, 0.f, 0.f};
    ushort_t* Pw = smem + 16384 + wave * (16 * 64);

    // Q A-frags (32 rows -> 2 m-tiles), loop-invariant
    bf16x8 aq[2][2];
#pragma unroll
    for (int mt = 0; mt < 2; ++mt) {
        const ushort_t* qrow = Qp + (size_t)(mbase + mt * 16 + lc) * DH_ + quad * 8;
        aq[mt][0] = *reinterpret_cast<const bf16x8*>(qrow);
        aq[mt][1] = *reinterpret_cast<const bf16x8*>(qrow + 32);
    }

    f32x4 o[2][4];
    float lsum[2][4];
#pragma unroll
    for (int mt = 0; mt < 2; ++mt) {
#pragma unroll
        for (int ct = 0; ct < 4; ++ct) o[mt][ct] = fzero;
#pragma unroll
        for (int r = 0; r < 4; ++r) lsum[mt][r] = 0.f;
    }

    // ---- per-thread staging geometry (round-invariant). Each thread stages
    // chunk tid and chunk 256+tid of each of the 4 tile regions. ----
    const int jj0 = tid,        jj1 = 256 + tid;
    const int rr0 = jj0 >> 3,   rr1 = jj1 >> 3;
    const int cc0 = (jj0 & 7) ^ (rr0 & 7), cc1 = (jj1 & 7) ^ (rr1 & 7);
    const int kp0 = 4 * (rr0 & 15) + (rr0 >> 4);   // K key-row permutation
    const int kp1 = 4 * (rr1 & 15) + (rr1 >> 4);
    const ushort_t* pK0 = Kp + kp0 * DH_ + cc0 * 8;         // + kt*4096
    const ushort_t* pK1 = Kp + kp1 * DH_ + cc1 * 8;
    const ushort_t* pV0 = Vp + (size_t)rr0 * T_ + cc0 * 8;  // + kt*64
    const ushort_t* pV1 = Vp + (size_t)rr1 * T_ + cc1 * 8;

    // 8 NAMED staging registers (rule #20: never an array)
    us8 sK0a, sK0b, sK1a, sK1b, sV0a, sV0b, sV1a, sV1b;

#define LOAD_KV(T0, T1)                                                      \
    {                                                                        \
        sK0a = *reinterpret_cast<const us8*>(pK0 + (T0) * 4096);             \
        sK0b = *reinterpret_cast<const us8*>(pK1 + (T0) * 4096);             \
        sK1a = *reinterpret_cast<const us8*>(pK0 + (T1) * 4096);             \
        sK1b = *reinterpret_cast<const us8*>(pK1 + (T1) * 4096);             \
        sV0a = *reinterpret_cast<const us8*>(pV0 + (T0) * 64);               \
        sV0b = *reinterpret_cast<const us8*>(pV1 + (T0) * 64);               \
        sV1a = *reinterpret_cast<const us8*>(pV0 + (T1) * 64);               \
        sV1b = *reinterpret_cast<const us8*>(pV1 + (T1) * 64);               \
    }

#define WRITE_KV()                                                           \
    {                                                                        \
        *reinterpret_cast<us8*>(smem + jj0 * 8)          = sK0a;             \
        *reinterpret_cast<us8*>(smem + jj1 * 8)          = sK0b;             \
        *reinterpret_cast<us8*>(smem + 4096 + jj0 * 8)   = sK1a;             \
        *reinterpret_cast<us8*>(smem + 4096 + jj1 * 8)   = sK1b;             \
        *reinterpret_cast<us8*>(smem + 8192 + jj0 * 8)   = sV0a;             \
        *reinterpret_cast<us8*>(smem + 8192 + jj1 * 8)   = sV0b;             \
        *reinterpret_cast<us8*>(smem + 12288 + jj0 * 8)  = sV1a;             \
        *reinterpret_cast<us8*>(smem + 12288 + jj1 * 8)  = sV1b;             \
    }

    // One k-tile of compute for this thread's group. diag folds to constant
    // at both inline sites (false in main loop, kt==qt in the tail).
    auto compute = [&](const int kt, const bool diag) {
        const int k0 = kt * 64;
        const ushort_t* Kt    = smem + grp * 4096;
        const ushort_t* Vtile = smem + 8192 + grp * 4096;

        // ---- S = Q K^T (K frags shared across m-tiles) ----
        f32x4 sc[2][4];
        __builtin_amdgcn_s_setprio(1);
#pragma unroll
        for (int ct = 0; ct < 4; ++ct) {
            const ushort_t* kr = Kt + (ct * 16 + lc) * 64;
            bf16x8 bk0 = *reinterpret_cast<const bf16x8*>(kr + ((quad ^ sw) * 8));
            bf16x8 bk1 = *reinterpret_cast<const bf16x8*>(kr + (((4 + quad) ^ sw) * 8));
#pragma unroll
            for (int mt = 0; mt < 2; ++mt) {
                sc[mt][ct] = __builtin_amdgcn_mfma_f32_16x16x32_bf16(aq[mt][0], bk0, fzero, 0, 0, 0);
                sc[mt][ct] = __builtin_amdgcn_mfma_f32_16x16x32_bf16(aq[mt][1], bk1, sc[mt][ct], 0, 0, 0);
            }
        }
        __builtin_amdgcn_s_setprio(0);

        // ---- V B-frags (needed only for PV; loaded here so the ds_reads
        // overlap softmax and don't hold 32 VGPRs across QK^T) ----
        bf16x8 bv[4][2];
#pragma unroll
        for (int ct = 0; ct < 4; ++ct) {
            const ushort_t* vr = Vtile + (ct * 16 + lc) * 64;
            bv[ct][0] = *reinterpret_cast<const bf16x8*>(vr + ((quad ^ sw) * 8));
            bv[ct][1] = *reinterpret_cast<const bf16x8*>(vr + (((4 + quad) ^ sw) * 8));
        }

        // ---- per m-tile: fixed-max softmax -> packed P write -> PV ----
#pragma unroll
        for (int mt = 0; mt < 2; ++mt) {
            float e[4][4];
            if (diag) {   // only the diagonal tile masks
#pragma unroll
                for (int ct = 0; ct < 4; ++ct) {
                    const int key = k0 + 4 * lc + ct;   // permuted key of this col
#pragma unroll
                    for (int r = 0; r < 4; ++r) {
                        const int row = mbase + mt * 16 + quad * 4 + r;
                        e[ct][r] = (key <= row) ? __builtin_amdgcn_exp2f(sc[mt][ct][r] * SC2) : 0.f;
                    }
                }
            } else {
#pragma unroll
                for (int ct = 0; ct < 4; ++ct)
#pragma unroll
                    for (int r = 0; r < 4; ++r)
                        e[ct][r] = __builtin_amdgcn_exp2f(sc[mt][ct][r] * SC2);
            }
            // P write: row-major 16 x 64 keys, 16 B-unit XOR swizzle
            // (physical_unit = (lc>>1) ^ (row&7)) keeps stride-64 bank-balanced.
#pragma unroll
            for (int r = 0; r < 4; ++r) {
                lsum[mt][r] += (e[0][r] + e[1][r]) + (e[2][r] + e[3][r]);
                unsigned lo = pack_bf16_2(e[0][r], e[1][r]);
                unsigned hi = pack_bf16_2(e[2][r], e[3][r]);
                const int row = quad * 4 + r;
                const int punit = (lc >> 1) ^ (row & 7);
                *reinterpret_cast<unsigned long long*>(
                    Pw + row * 64 + punit * 8 + (lc & 1) * 4) =
                    (unsigned long long)lo | ((unsigned long long)hi << 32);
            }
            // P read: q-row = lc; frag0 = keys quad*8.., frag1 = keys 32+quad*8..
            bf16x8 ap0 = *reinterpret_cast<const bf16x8*>(
                Pw + lc * 64 + ((quad ^ (lc & 7)) * 8));
            bf16x8 ap1 = *reinterpret_cast<const bf16x8*>(
                Pw + lc * 64 + (((4 + quad) ^ (lc & 7)) * 8));
            __builtin_amdgcn_s_setprio(1);
#pragma unroll
            for (int ct = 0; ct < 4; ++ct) {
                o[mt][ct] = __builtin_amdgcn_mfma_f32_16x16x32_bf16(ap0, bv[ct][0], o[mt][ct], 0, 0, 0);
                o[mt][ct] = __builtin_amdgcn_mfma_f32_16x16x32_bf16(ap1, bv[ct][1], o[mt][ct], 0, 0, 0);
            }
            __builtin_amdgcn_s_setprio(0);
        }
    };

    // ---- prologue: stage round 0 ----
    {
        const int t1 = (nkt > 1) ? 1 : 0;
        LOAD_KV(0, t1);
        WRITE_KV();
        __syncthreads();   // round-0 tiles visible
    }

    // ---- main loop: straight-line, unmasked, unguarded ----
    for (int it = 0; it < nIt - 1; ++it) {
        const int n0t = 2 * it + 2;
        const int n1t = (n0t + 1 < nkt) ? n0t + 1 : n0t;
        LOAD_KV(n0t, n1t);            // next round, in flight under compute
        compute(2 * it + grp, false); // kt < qt guaranteed here
        __syncthreads();              // all waves done reading current tiles
        WRITE_KV();                   // vmcnt wait is compiler-inserted here
        __syncthreads();              // next round's tiles visible
    }

    // ---- peeled last round: guard + causal mask, no prefetch ----
    {
        const int ktL = 2 * (nIt - 1) + grp;
        if (ktL < nkt) compute(ktL, ktL == qt);
    }
#undef LOAD_KV
#undef WRITE_KV

    // ---- combine the two k-groups via LDS; group 1 normalizes; coalesced store ----
    __syncthreads();   // compute done; K/V LDS reusable as scratch
    float* Osh = (float*)smem;             // 16 KB (K region)
    float* Lsh = (float*)(smem + 8192);    // 4 KB (V region)
    ushort_t* Fsh = smem + 16384;          // 8 KB final bf16 tile (P region reuse)
    if (grp == 0) {
#pragma unroll
        for (int mt = 0; mt < 2; ++mt) {
#pragma unroll
            for (int ct = 0; ct < 4; ++ct)
#pragma unroll
                for (int r = 0; r < 4; ++r)
                    Osh[(sub * 32 + mt * 16 + quad * 4 + r) * 64 + ct * 16 + lc] = o[mt][ct][r];
#pragma unroll
            for (int r = 0; r < 4; ++r)
                Lsh[(sub * 32 + mt * 16 + quad * 4 + r) * 16 + lc] = lsum[mt][r];
        }
    }
    __syncthreads();
    if (grp == 1) {
#pragma unroll
        for (int mt = 0; mt < 2; ++mt) {
            float inv[4];
#pragma unroll
            for (int r = 0; r < 4; ++r) {
                float l = lsum[mt][r] + Lsh[(sub * 32 + mt * 16 + quad * 4 + r) * 16 + lc];
#pragma unroll
                for (int d = 1; d < 16; d <<= 1) l += __shfl_xor(l, d);
                inv[r] = 1.0f / l;
            }
#pragma unroll
            for (int ct = 0; ct < 4; ++ct)
#pragma unroll
                for (int r = 0; r < 4; ++r) {
                    const int row = sub * 32 + mt * 16 + quad * 4 + r;   // 0..63 local
                    const float ov = o[mt][ct][r] + Osh[row * 64 + ct * 16 + lc];
                    const int cu = ct * 16 + lc;
                    // XOR-swizzle the 8-ushort chunk index by row so the
                    // vectorized read below is bank-conflict-free
                    Fsh[row * 64 + ((cu & 7) | ((((cu >> 3) ^ row) & 7) << 3))] =
                        f32_to_bf16_rne(ov * inv[r]);
                }
        }
    }
    __syncthreads();
    // 64 rows x 128 B contiguous stores (full sectors): 512 chunks of 16 B
#pragma unroll
    for (int i = 0; i < 2; ++i) {
        const int j = i * 256 + tid;
        const int row = j >> 3, c8 = j & 7;
        us8 vv = *reinterpret_cast<const us8*>(Fsh + row * 64 + ((c8 ^ row) & 7) * 8);
        *reinterpret_cast<us8*>(Ao + ((size_t)bb * T_ + q0 + row) * D_ + hh * DH_ + c8 * 8) = vv;
    }
}

// ---------------- launch ----------------
extern "C" void kernel_launch(void* const* d_in, const int* in_sizes, int n_in,
                              void* d_out, int out_size, void* d_ws, size_t ws_size,
                              hipStream_t stream) {
    const float* q  = (const float*)d_in[0];
    const float* k  = (const float*)d_in[1];
    const float* v  = (const float*)d_in[2];
    const float* wq = (const float*)d_in[3];
    const float* wk = (const float*)d_in[4];
    const float* wv = (const float*)d_in[5];
    const float* wo = (const float*)d_in[6];

    char* ws = (char*)d_ws;
    size_t off = 0;
    auto alloc = [&](size_t bytes) -> char* {
        char* p = ws + off;
        off += (bytes + 255) & ~(size_t)255;
        return p;
    };
    ushort_t* qb  = (ushort_t*)alloc((size_t)M_ * D_ * 2);
    ushort_t* kb  = (ushort_t*)alloc((size_t)M_ * D_ * 2);
    ushort_t* vb  = (ushort_t*)alloc((size_t)M_ * D_ * 2);
    ushort_t* wqb = (ushort_t*)alloc((size_t)D_ * D_ * 2);
    ushort_t* wkb = (ushort_t*)alloc((size_t)D_ * D_ * 2);
    ushort_t* wvb = (ushort_t*)alloc((size_t)D_ * D_ * 2);
    ushort_t* wob = (ushort_t*)alloc((size_t)D_ * D_ * 2);
    ushort_t* qhb = (ushort_t*)alloc((size_t)M_ * D_ * 2);  // [B,H,T,DH]
    ushort_t* khb = (ushort_t*)alloc((size_t)M_ * D_ * 2);  // [B,H,T,DH]
    ushort_t* vtb = (ushort_t*)alloc((size_t)M_ * D_ * 2);  // [B,H,DH,T]
    ushort_t* aob = (ushort_t*)alloc((size_t)M_ * D_ * 2);  // [B,T,D]

    cvt_all<<<dim3(4096, 7), 256, 0, stream>>>(q, k, v, wq, wk, wv, wo,
                                               qb, kb, vb, wqb, wkb, wvb, wob);

    gemm_qkv<<<dim3(8, 32, 3), 256, 0, stream>>>(qb, kb, vb, wqb, wkb, wvb, qhb, khb, vtb);

    attn11<<<dim3(1024), 256, 0, stream>>>(qhb, khb, vtb, aob);

    gemm_wo<<<dim3(8, 64), 256, 0, stream>>>(aob, wob, (float*)d_out);
}